// Round 10
// baseline (235.876 us; speedup 1.0000x reference)
//
#include <hip/hip_runtime.h>

#define HIDDEN 128
#define NBUCKETS 20

typedef unsigned int uint32;
typedef unsigned short u16;
typedef unsigned long long u64;
typedef __attribute__((ext_vector_type(8))) short bf16x8;
typedef __attribute__((ext_vector_type(4))) float f32x4;

__device__ __forceinline__ u16 f32_to_bf16(float f) {
    uint32 u = __float_as_uint(f);
    return (u16)((u + 0x7fffu + ((u >> 16) & 1u)) >> 16);
}
__device__ __forceinline__ float bf_lo(uint32 u) { return __uint_as_float(u << 16); }
__device__ __forceinline__ float bf_hi(uint32 u) { return __uint_as_float(u & 0xffff0000u); }

// k1: W1T transpose+convert, zero cnt, de_dot.
__global__ void prep_kernel(const float* __restrict__ W1, u16* __restrict__ W1T,
                            int* __restrict__ cnt, int n_nodes,
                            const float* __restrict__ table,
                            const float* __restrict__ W2,
                            float* __restrict__ de_dot) {
    int idx = blockIdx.x * 256 + threadIdx.x;
    int n = idx >> 7, k = idx & 127;
    int srow = (n < 128) ? k : (128 + k);
    W1T[idx] = f32_to_bf16(W1[srow * HIDDEN + (n & 127)]);
    for (int i = idx; i < n_nodes; i += 32768) cnt[i] = 0;
    if (blockIdx.x == 0 && threadIdx.x < NBUCKETS) {
        float a = 0.f;
        for (int kk = 0; kk < HIDDEN; ++kk)
            a = fmaf(table[threadIdx.x * HIDDEN + kk], W2[HIDDEN + kk], a);
        de_dot[threadIdx.x] = a;
    }
}

// k2: fused degree-histogram + MFMA GEMM (one 16-row tile/block).
__global__ __launch_bounds__(256)
void gemm_count_kernel(const float* __restrict__ x, const u16* __restrict__ W1T,
                       const int* __restrict__ tgt, int* __restrict__ cnt,
                       u16* __restrict__ y16, u16* __restrict__ z16,
                       u16* __restrict__ x16, int n_nodes, int n_edges) {
    __shared__ bf16x8 lds_a[16][16];
    __shared__ u16 lds_c[4][16][72];

    int tid = threadIdx.x;
    int e = blockIdx.x * 256 + tid;
    if (e < n_edges) atomicAdd(&cnt[tgt[e]], 1);

    int row_base = blockIdx.x * 16;
    if (row_base >= n_nodes) return;

    {
        int row = tid >> 4, c = tid & 15;
        int node = row_base + row;
        bf16x8 a = {};
        if (node < n_nodes) {
            const float4* xp = (const float4*)(x + (size_t)node * HIDDEN + c * 8);
            float4 v0 = xp[0], v1 = xp[1];
            a[0] = (short)f32_to_bf16(v0.x); a[1] = (short)f32_to_bf16(v0.y);
            a[2] = (short)f32_to_bf16(v0.z); a[3] = (short)f32_to_bf16(v0.w);
            a[4] = (short)f32_to_bf16(v1.x); a[5] = (short)f32_to_bf16(v1.y);
            a[6] = (short)f32_to_bf16(v1.z); a[7] = (short)f32_to_bf16(v1.w);
            *(bf16x8*)(x16 + (size_t)node * HIDDEN + c * 8) = a;
        }
        lds_a[c][row] = a;
    }
    __syncthreads();

    int wave = tid >> 6, lane = tid & 63;
    int m = lane & 15, kb = lane >> 4;

    bf16x8 afrag[4];
#pragma unroll
    for (int ks = 0; ks < 4; ++ks) afrag[ks] = lds_a[ks * 4 + kb][m];

#pragma unroll
    for (int ci = 0; ci < 4; ++ci) {
        int col = wave * 64 + ci * 16 + m;
        const u16* bp = W1T + (size_t)col * HIDDEN + kb * 8;
        f32x4 acc = {0.f, 0.f, 0.f, 0.f};
#pragma unroll
        for (int ks = 0; ks < 4; ++ks) {
            bf16x8 b = *(const bf16x8*)(bp + ks * 32);
            acc = __builtin_amdgcn_mfma_f32_16x16x32_bf16(afrag[ks], b, acc, 0, 0, 0);
        }
#pragma unroll
        for (int e2 = 0; e2 < 4; ++e2)
            lds_c[wave][kb * 4 + e2][ci * 16 + m] = f32_to_bf16(acc[e2]);
    }
    __syncthreads();

    {
        int r = lane >> 2, q = lane & 3;
        const u16* src = &lds_c[wave][r][q * 16];
        bf16x8 c0 = *(const bf16x8*)(src);
        bf16x8 c1 = *(const bf16x8*)(src + 8);
        int node = row_base + r;
        int colg = wave * 64 + q * 16;
        if (node < n_nodes) {
            u16* dst = (colg < HIDDEN) ? (y16 + (size_t)node * HIDDEN + colg)
                                       : (z16 + (size_t)node * HIDDEN + colg - HIDDEN);
            *(bf16x8*)dst = c0;
            *(bf16x8*)(dst + 8) = c1;
        }
    }
}

// k3: per-block exclusive prescan of cnt + block totals; re-zero cnt (cursor reuse).
__global__ void scan_blocks_kernel(int* __restrict__ cnt,
                                   int* __restrict__ prescan,
                                   int* __restrict__ partial,
                                   int n_nodes) {
    __shared__ int sh[256];
    int t = threadIdx.x;
    int i = blockIdx.x * 256 + t;
    int v = (i < n_nodes) ? cnt[i] : 0;
    sh[t] = v;
    __syncthreads();
    for (int d = 1; d < 256; d <<= 1) {
        int add = (t >= d) ? sh[t - d] : 0;
        __syncthreads();
        sh[t] += add;
        __syncthreads();
    }
    if (i < n_nodes) { prescan[i] = sh[t] - v; cnt[i] = 0; }
    if (t == 255) partial[blockIdx.x] = sh[t];
}

// k4: exclusive scan of block totals (nb <= 256).
__global__ void scan_partials_kernel(int* __restrict__ partial, int nb) {
    __shared__ int sh[256];
    int t = threadIdx.x;
    int v = (t < nb) ? partial[t] : 0;
    sh[t] = v;
    __syncthreads();
    for (int d = 1; d < 256; d <<= 1) {
        int add = (t >= d) ? sh[t - d] : 0;
        __syncthreads();
        sh[t] += add;
        __syncthreads();
    }
    if (t < nb) partial[t] = sh[t] - v;
}

// k5: scatter edges into CSR order; record packs {ded_f32:32, s:32}.
__global__ void scatter_kernel(const int* __restrict__ edge_index,
                               const int* __restrict__ distances,
                               const int* __restrict__ prescan,
                               const int* __restrict__ partial,
                               const float* __restrict__ de_dot,
                               int* __restrict__ cnt,
                               u64* __restrict__ csr_sd,
                               int n_edges) {
    int e = blockIdx.x * blockDim.x + threadIdx.x;
    if (e >= n_edges) return;
    int s = edge_index[e];
    int t = edge_index[n_edges + e];
    float ded = de_dot[distances[e] / 50];
    int base = prescan[t] + partial[t >> 8];
    int pos = atomicAdd(&cnt[t], 1);
    csr_sd[base + pos] = ((u64)__float_as_uint(ded) << 32) | (uint32)s;
}

// k6: fused per-node attention+aggregation, 16-edge batched LDS-transpose
// logit reduction. Fully statically-unrolled (NO break -> xreg/yreg stay in
// VGPRs, rule #20); load-loop separated from compute-loop for deep MLP;
// 4-way split accumulators in Phase C.
__global__ __launch_bounds__(256)
void aggregate_kernel(const u16* __restrict__ x16,
                      const u16* __restrict__ y16,
                      const u16* __restrict__ z16,
                      const float* __restrict__ W2,
                      const u64* __restrict__ csr_sd,
                      const int* __restrict__ prescan,
                      const int* __restrict__ partial,
                      const int* __restrict__ cnt,
                      float* __restrict__ out,
                      int n_nodes) {
    __shared__ float lds_p[4][16][68];   // [wave][edge][lane col + pad]
    int wave = threadIdx.x >> 6, lane = threadIdx.x & 63;
    int t = blockIdx.x * 4 + wave;
    if (t >= n_nodes) return;

    int base = prescan[t] + partial[t >> 8];
    int deg = cnt[t];
    const uint32* __restrict__ yp = (const uint32*)y16;
    const uint32* __restrict__ xp = (const uint32*)x16;

    uint32 zv = ((const uint32*)z16)[(size_t)t * 64 + lane];
    float z0 = bf_lo(zv), z1 = bf_hi(zv);
    float2 wv = *(const float2*)(W2 + lane * 2);
    float (*P)[68] = lds_p[wave];

    float acc0a = 0.f, acc1a = 0.f, acc0b = 0.f, acc1b = 0.f;
    float acc0c = 0.f, acc1c = 0.f, acc0d = 0.f, acc1d = 0.f;
    float attsum = 0.f;

    for (int b = 0; b < deg; b += 64) {
        int nb = min(64, deg - b);
        int s_l = 0; float ded_l = 0.f;
        if (lane < nb) {
            uint2 rec = *(const uint2*)(csr_sd + base + b + lane);
            s_l = (int)rec.x;
            ded_l = __uint_as_float(rec.y);
        }
        for (int sb = 0; sb < nb; sb += 16) {
            int c16 = min(16, nb - sb);
            uint32 yreg[16], xreg[16];
            // Phase A1: issue all 32 independent gathers (static unroll,
            // wave-uniform predication -> no scratch, deep MLP).
#pragma unroll
            for (int j = 0; j < 16; ++j) {
                yreg[j] = 0u; xreg[j] = 0u;
                if (j < c16) {
                    int sj = __shfl(s_l, sb + j, 64);
                    yreg[j] = yp[(size_t)sj * 64 + lane];
                    xreg[j] = xp[(size_t)sj * 64 + lane];
                }
            }
            // Phase A2: per-edge 2-feature partial -> LDS[j][lane].
#pragma unroll
            for (int j = 0; j < 16; ++j) {
                float h0 = bf_lo(yreg[j]) + z0; h0 = fmaxf(h0, 0.2f * h0);
                float h1 = bf_hi(yreg[j]) + z1; h1 = fmaxf(h1, 0.2f * h1);
                P[j][lane] = fmaf(h0, wv.x, h1 * wv.y);
            }
            // Phase B: lane L reduces edge (L&15) over cols (L>>4)*16..+16,
            // 2-step cross-group reduce; sigmoid/exp once per 16 edges.
            const float4* pr = (const float4*)(P[lane & 15] + ((lane >> 4) << 4));
            float4 q0 = pr[0], q1 = pr[1], q2 = pr[2], q3 = pr[3];
            float s4 = ((q0.x + q0.y) + (q0.z + q0.w))
                     + ((q1.x + q1.y) + (q1.z + q1.w))
                     + ((q2.x + q2.y) + (q2.z + q2.w))
                     + ((q3.x + q3.y) + (q3.z + q3.w));
            s4 += __shfl_xor(s4, 16, 64);
            s4 += __shfl_xor(s4, 32, 64);
            float ded_e = __shfl(ded_l, sb + (lane & 15), 64);
            float att = __expf(1.f / (1.f + __expf(-(s4 + ded_e))));
            att = ((lane & 15) < c16) ? att : 0.f;
            attsum += (lane < 16) ? att : 0.f;
            // Phase C: broadcast att, accumulate stashed x (4 parallel chains).
#pragma unroll
            for (int j = 0; j < 16; j += 4) {
                float aA = __shfl(att, j, 64);
                float aB = __shfl(att, j + 1, 64);
                float aC = __shfl(att, j + 2, 64);
                float aD = __shfl(att, j + 3, 64);
                acc0a = fmaf(aA, bf_lo(xreg[j]), acc0a);
                acc1a = fmaf(aA, bf_hi(xreg[j]), acc1a);
                acc0b = fmaf(aB, bf_lo(xreg[j + 1]), acc0b);
                acc1b = fmaf(aB, bf_hi(xreg[j + 1]), acc1b);
                acc0c = fmaf(aC, bf_lo(xreg[j + 2]), acc0c);
                acc1c = fmaf(aC, bf_hi(xreg[j + 2]), acc1c);
                acc0d = fmaf(aD, bf_lo(xreg[j + 3]), acc0d);
                acc1d = fmaf(aD, bf_hi(xreg[j + 3]), acc1d);
            }
        }
    }
    float acc0 = (acc0a + acc0b) + (acc0c + acc0d);
    float acc1 = (acc1a + acc1b) + (acc1c + acc1d);
#pragma unroll
    for (int off = 32; off > 0; off >>= 1) attsum += __shfl_xor(attsum, off, 64);
    float inv = 1.f / (attsum + 1e-6f);
    float2 o;
    o.x = fmaxf(acc0 * inv, 0.f);
    o.y = fmaxf(acc1 * inv, 0.f);
    *(float2*)(out + (size_t)t * HIDDEN + lane * 2) = o;
}

static inline size_t align16(size_t v) { return (v + 15) & ~(size_t)15; }

extern "C" void kernel_launch(void* const* d_in, const int* in_sizes, int n_in,
                              void* d_out, int out_size, void* d_ws, size_t ws_size,
                              hipStream_t stream) {
    const float* x          = (const float*)d_in[0];
    const int*   edge_index = (const int*)d_in[1];
    const int*   distances  = (const int*)d_in[2];
    const float* W1         = (const float*)d_in[3];
    const float* W2         = (const float*)d_in[4];
    const float* table      = (const float*)d_in[5];

    int n_nodes = in_sizes[0] / HIDDEN;
    int n_edges = in_sizes[1] / 2;
    float* out = (float*)d_out;

    // Workspace layout (16B-aligned sections)
    char* p = (char*)d_ws;
    int* cnt      = (int*)p;                 p += align16((size_t)n_nodes * 4);
    int* prescan  = (int*)p;                 p += align16((size_t)n_nodes * 4);
    int* partial  = (int*)p;                 p += align16(256 * 4);
    u64* csr_sd   = (u64*)p;                 p += align16((size_t)n_edges * 8);
    float* de_dot  = (float*)p;              p += align16(32 * 4);
    u16* W1T       = (u16*)p;                p += align16(256 * HIDDEN * 2);
    u16* y16       = (u16*)p;                p += align16((size_t)n_nodes * HIDDEN * 2);
    u16* z16       = (u16*)p;                p += align16((size_t)n_nodes * HIDDEN * 2);
    u16* x16       = (u16*)p;

    const int* tgt = edge_index + n_edges;

    prep_kernel<<<128, 256, 0, stream>>>(W1, W1T, cnt, n_nodes, table, W2, de_dot);

    int ntiles = (n_nodes + 15) / 16;
    int eblocks = (n_edges + 255) / 256;
    int gblocks = (ntiles > eblocks) ? ntiles : eblocks;
    gemm_count_kernel<<<gblocks, 256, 0, stream>>>(x, W1T, tgt, cnt,
                                                   y16, z16, x16, n_nodes, n_edges);

    int nb = (n_nodes + 255) / 256;
    scan_blocks_kernel<<<nb, 256, 0, stream>>>(cnt, prescan, partial, n_nodes);
    scan_partials_kernel<<<1, 256, 0, stream>>>(partial, nb);

    scatter_kernel<<<eblocks, 256, 0, stream>>>(
        edge_index, distances, prescan, partial, de_dot, cnt, csr_sd, n_edges);

    int ablocks = (n_nodes + 3) / 4;
    aggregate_kernel<<<ablocks, 256, 0, stream>>>(
        x16, y16, z16, W2, csr_sd, prescan, partial, cnt, out, n_nodes);
}

// Round 11
// 196.179 us; speedup vs baseline: 1.2023x; 1.2023x over previous
//
#include <hip/hip_runtime.h>

#define HIDDEN 128
#define NBUCKETS 20

typedef unsigned int uint32;
typedef unsigned short u16;
typedef unsigned long long u64;
typedef __attribute__((ext_vector_type(8))) short bf16x8;
typedef __attribute__((ext_vector_type(4))) float f32x4;

__device__ __forceinline__ u16 f32_to_bf16(float f) {
    uint32 u = __float_as_uint(f);
    return (u16)((u + 0x7fffu + ((u >> 16) & 1u)) >> 16);
}
__device__ __forceinline__ float bf_lo(uint32 u) { return __uint_as_float(u << 16); }
__device__ __forceinline__ float bf_hi(uint32 u) { return __uint_as_float(u & 0xffff0000u); }

// k1: W1T transpose+convert; zero cnt/cur/gcur; de_dot.
__global__ void prep_kernel(const float* __restrict__ W1, u16* __restrict__ W1T,
                            int* __restrict__ cnt, int* __restrict__ cur,
                            int* __restrict__ gcur, int n_nodes,
                            const float* __restrict__ table,
                            const float* __restrict__ W2,
                            float* __restrict__ de_dot) {
    int idx = blockIdx.x * 256 + threadIdx.x;
    int n = idx >> 7, k = idx & 127;
    int srow = (n < 128) ? k : (128 + k);
    W1T[idx] = f32_to_bf16(W1[srow * HIDDEN + (n & 127)]);
    for (int i = idx; i < n_nodes; i += 32768) { cnt[i] = 0; cur[i] = 0; }
    if (idx == 0) *gcur = 0;
    if (blockIdx.x == 0 && threadIdx.x < NBUCKETS) {
        float a = 0.f;
        for (int kk = 0; kk < HIDDEN; ++kk)
            a = fmaf(table[threadIdx.x * HIDDEN + kk], W2[HIDDEN + kk], a);
        de_dot[threadIdx.x] = a;
    }
}

// k2: fused degree-histogram + MFMA GEMM (one 16-row tile/block).
// Emits interleaved xy (per node: 64 x uint2 {x_pair, y_pair}) and z16.
__global__ __launch_bounds__(256)
void gemm_count_kernel(const float* __restrict__ x, const u16* __restrict__ W1T,
                       const int* __restrict__ tgt, int* __restrict__ cnt,
                       uint32* __restrict__ xyu, u16* __restrict__ z16,
                       int n_nodes, int n_edges) {
    __shared__ bf16x8 lds_a[16][16];
    __shared__ u16 lds_c[4][16][72];

    int tid = threadIdx.x;
    int e = blockIdx.x * 256 + tid;
    if (e < n_edges) atomicAdd(&cnt[tgt[e]], 1);

    int row_base = blockIdx.x * 16;
    if (row_base >= n_nodes) return;

    // A staging: thread -> (row = tid>>4, k-chunk c = tid&15).
    // Also writes x-halves of xy (4 dwords, stride 8B).
    {
        int row = tid >> 4, c = tid & 15;
        int node = row_base + row;
        bf16x8 a = {};
        if (node < n_nodes) {
            const float4* xp = (const float4*)(x + (size_t)node * HIDDEN + c * 8);
            float4 v0 = xp[0], v1 = xp[1];
            a[0] = (short)f32_to_bf16(v0.x); a[1] = (short)f32_to_bf16(v0.y);
            a[2] = (short)f32_to_bf16(v0.z); a[3] = (short)f32_to_bf16(v0.w);
            a[4] = (short)f32_to_bf16(v1.x); a[5] = (short)f32_to_bf16(v1.y);
            a[6] = (short)f32_to_bf16(v1.z); a[7] = (short)f32_to_bf16(v1.w);
            const uint32* au = (const uint32*)&a;
            uint32* xb = xyu + (size_t)node * 128 + c * 8;   // slot c*4+d -> dword (c*4+d)*2
#pragma unroll
            for (int d = 0; d < 4; ++d) xb[d * 2] = au[d];
        }
        lds_a[c][row] = a;
    }
    __syncthreads();

    int wave = tid >> 6, lane = tid & 63;
    int m = lane & 15, kb = lane >> 4;

    bf16x8 afrag[4];
#pragma unroll
    for (int ks = 0; ks < 4; ++ks) afrag[ks] = lds_a[ks * 4 + kb][m];

#pragma unroll
    for (int ci = 0; ci < 4; ++ci) {
        int col = wave * 64 + ci * 16 + m;
        const u16* bp = W1T + (size_t)col * HIDDEN + kb * 8;
        f32x4 acc = {0.f, 0.f, 0.f, 0.f};
#pragma unroll
        for (int ks = 0; ks < 4; ++ks) {
            bf16x8 b = *(const bf16x8*)(bp + ks * 32);
            acc = __builtin_amdgcn_mfma_f32_16x16x32_bf16(afrag[ks], b, acc, 0, 0, 0);
        }
#pragma unroll
        for (int e2 = 0; e2 < 4; ++e2)
            lds_c[wave][kb * 4 + e2][ci * 16 + m] = f32_to_bf16(acc[e2]);
    }
    __syncthreads();

    // C readback: lane -> (row r = lane>>2, 16-col seg q = lane&3).
    {
        int r = lane >> 2, q = lane & 3;
        const u16* src = &lds_c[wave][r][q * 16];
        bf16x8 c0 = *(const bf16x8*)(src);
        bf16x8 c1 = *(const bf16x8*)(src + 8);
        int node = row_base + r;
        int colg = wave * 64 + q * 16;
        if (node < n_nodes) {
            if (colg < HIDDEN) {
                // y-halves of xy: 8 dwords, stride 8B, offset +1.
                const uint32* cu0 = (const uint32*)&c0;
                const uint32* cu1 = (const uint32*)&c1;
                uint32* yb = xyu + (size_t)node * 128 + colg + 1;  // slot colg/2 -> dword colg
#pragma unroll
                for (int i = 0; i < 4; ++i) yb[i * 2] = cu0[i];
#pragma unroll
                for (int i = 0; i < 4; ++i) yb[8 + i * 2] = cu1[i];
            } else {
                u16* dst = z16 + (size_t)node * HIDDEN + colg - HIDDEN;
                *(bf16x8*)dst = c0;
                *(bf16x8*)(dst + 8) = c1;
            }
        }
    }
}

// k3: segment-base allocation: wave prefix-sum of degrees + one global atomic
// per wave. Segment order nondeterministic; per-node output unaffected.
__global__ void alloc_kernel(const int* __restrict__ cnt, int* __restrict__ base,
                             int* __restrict__ gcur, int n_nodes) {
    int i = blockIdx.x * 256 + threadIdx.x;
    int lane = threadIdx.x & 63;
    int deg = (i < n_nodes) ? cnt[i] : 0;
    int pre = deg;
#pragma unroll
    for (int d = 1; d < 64; d <<= 1) {
        int v = __shfl_up(pre, d, 64);
        if (lane >= d) pre += v;
    }
    int total = __shfl(pre, 63, 64);
    int wbase = 0;
    if (lane == 63) wbase = atomicAdd(gcur, total);
    wbase = __shfl(wbase, 63, 64);
    if (i < n_nodes) base[i] = wbase + pre - deg;
}

// k4: scatter edges into CSR order; record packs {ded_f32:32, s:32}.
__global__ void scatter_kernel(const int* __restrict__ edge_index,
                               const int* __restrict__ distances,
                               const int* __restrict__ base,
                               const float* __restrict__ de_dot,
                               int* __restrict__ cur,
                               u64* __restrict__ csr_sd,
                               int n_edges) {
    int e = blockIdx.x * blockDim.x + threadIdx.x;
    if (e >= n_edges) return;
    int s = edge_index[e];
    int t = edge_index[n_edges + e];
    float ded = de_dot[distances[e] / 50];
    int pos = atomicAdd(&cur[t], 1);
    csr_sd[base[t] + pos] = ((u64)__float_as_uint(ded) << 32) | (uint32)s;
}

// k5: one wave per node: fused attention + aggregation + normalize + relu.
// Single 8B xy gather per edge per lane; edge loop unrolled x2 for ILP.
__global__ void aggregate_kernel(const uint32* __restrict__ xyu,
                                 const u16* __restrict__ z16,
                                 const float* __restrict__ W2,
                                 const u64* __restrict__ csr_sd,
                                 const int* __restrict__ base_a,
                                 const int* __restrict__ cnt,
                                 float* __restrict__ out,
                                 int n_nodes) {
    int lane = threadIdx.x & 63;
    int t = blockIdx.x * (blockDim.x >> 6) + (threadIdx.x >> 6);
    if (t >= n_nodes) return;

    int base = base_a[t];
    int deg = cnt[t];
    const uint2* __restrict__ xyp = (const uint2*)xyu;

    uint32 zv = ((const uint32*)z16)[(size_t)t * 64 + lane];
    float z0 = bf_lo(zv), z1 = bf_hi(zv);
    float2 wv = *(const float2*)(W2 + lane * 2);

    float acc0 = 0.f, acc1 = 0.f, attsum = 0.f;

    for (int b = 0; b < deg; b += 64) {
        int nb = min(64, deg - b);
        int s_l = 0;
        float ded_l = 0.f;
        if (lane < nb) {
            uint2 rec = *(const uint2*)(csr_sd + base + b + lane);
            s_l = (int)rec.x;
            ded_l = __uint_as_float(rec.y);
        }
        int j = 0;
        for (; j + 2 <= nb; j += 2) {
            int sA = __shfl(s_l, j, 64);
            int sB = __shfl(s_l, j + 1, 64);
            float dA = __shfl(ded_l, j, 64);
            float dB = __shfl(ded_l, j + 1, 64);
            uint2 va = xyp[(size_t)sA * 64 + lane];   // {x pair, y pair}
            uint2 vb = xyp[(size_t)sB * 64 + lane];
            float hA0 = bf_lo(va.y) + z0, hA1 = bf_hi(va.y) + z1;
            float hB0 = bf_lo(vb.y) + z0, hB1 = bf_hi(vb.y) + z1;
            hA0 = fmaxf(hA0, 0.2f * hA0); hA1 = fmaxf(hA1, 0.2f * hA1);
            hB0 = fmaxf(hB0, 0.2f * hB0); hB1 = fmaxf(hB1, 0.2f * hB1);
            float pA = fmaf(hA0, wv.x, hA1 * wv.y);
            float pB = fmaf(hB0, wv.x, hB1 * wv.y);
#pragma unroll
            for (int off = 32; off > 0; off >>= 1) {
                pA += __shfl_xor(pA, off, 64);
                pB += __shfl_xor(pB, off, 64);
            }
            float sigA = 1.f / (1.f + __expf(-(pA + dA)));
            float sigB = 1.f / (1.f + __expf(-(pB + dB)));
            float attA = __expf(sigA);
            float attB = __expf(sigB);
            acc0 = fmaf(attA, bf_lo(va.x), acc0);
            acc1 = fmaf(attA, bf_hi(va.x), acc1);
            acc0 = fmaf(attB, bf_lo(vb.x), acc0);
            acc1 = fmaf(attB, bf_hi(vb.x), acc1);
            attsum += attA + attB;
        }
        for (; j < nb; ++j) {
            int sA = __shfl(s_l, j, 64);
            float dA = __shfl(ded_l, j, 64);
            uint2 va = xyp[(size_t)sA * 64 + lane];
            float hA0 = bf_lo(va.y) + z0, hA1 = bf_hi(va.y) + z1;
            hA0 = fmaxf(hA0, 0.2f * hA0); hA1 = fmaxf(hA1, 0.2f * hA1);
            float pA = fmaf(hA0, wv.x, hA1 * wv.y);
#pragma unroll
            for (int off = 32; off > 0; off >>= 1) pA += __shfl_xor(pA, off, 64);
            float attA = __expf(1.f / (1.f + __expf(-(pA + dA))));
            acc0 = fmaf(attA, bf_lo(va.x), acc0);
            acc1 = fmaf(attA, bf_hi(va.x), acc1);
            attsum += attA;
        }
    }
    float inv = 1.f / (attsum + 1e-6f);
    float2 o;
    o.x = fmaxf(acc0 * inv, 0.f);
    o.y = fmaxf(acc1 * inv, 0.f);
    *(float2*)(out + (size_t)t * HIDDEN + lane * 2) = o;
}

static inline size_t align16(size_t v) { return (v + 15) & ~(size_t)15; }

extern "C" void kernel_launch(void* const* d_in, const int* in_sizes, int n_in,
                              void* d_out, int out_size, void* d_ws, size_t ws_size,
                              hipStream_t stream) {
    const float* x          = (const float*)d_in[0];
    const int*   edge_index = (const int*)d_in[1];
    const int*   distances  = (const int*)d_in[2];
    const float* W1         = (const float*)d_in[3];
    const float* W2         = (const float*)d_in[4];
    const float* table      = (const float*)d_in[5];

    int n_nodes = in_sizes[0] / HIDDEN;
    int n_edges = in_sizes[1] / 2;
    float* out = (float*)d_out;

    // Workspace layout (16B-aligned sections)
    char* p = (char*)d_ws;
    int* cnt      = (int*)p;                 p += align16((size_t)n_nodes * 4);
    int* cur      = (int*)p;                 p += align16((size_t)n_nodes * 4);
    int* basea    = (int*)p;                 p += align16((size_t)n_nodes * 4);
    int* gcur     = (int*)p;                 p += align16(16 * 4);
    u64* csr_sd   = (u64*)p;                 p += align16((size_t)n_edges * 8);
    float* de_dot = (float*)p;               p += align16(32 * 4);
    u16* W1T      = (u16*)p;                 p += align16(256 * HIDDEN * 2);
    u16* z16      = (u16*)p;                 p += align16((size_t)n_nodes * HIDDEN * 2);
    uint32* xyu   = (uint32*)p;              // n_nodes * 128 dwords (x/y interleaved)

    const int* tgt = edge_index + n_edges;

    prep_kernel<<<128, 256, 0, stream>>>(W1, W1T, cnt, cur, gcur, n_nodes,
                                         table, W2, de_dot);

    int ntiles = (n_nodes + 15) / 16;
    int eblocks = (n_edges + 255) / 256;
    int gblocks = (ntiles > eblocks) ? ntiles : eblocks;
    gemm_count_kernel<<<gblocks, 256, 0, stream>>>(x, W1T, tgt, cnt,
                                                   xyu, z16, n_nodes, n_edges);

    alloc_kernel<<<(n_nodes + 255) / 256, 256, 0, stream>>>(cnt, basea, gcur, n_nodes);

    scatter_kernel<<<eblocks, 256, 0, stream>>>(
        edge_index, distances, basea, de_dot, cur, csr_sd, n_edges);

    const int waves_per_block = 4;
    int ablocks = (n_nodes + waves_per_block - 1) / waves_per_block;
    aggregate_kernel<<<ablocks, 64 * waves_per_block, 0, stream>>>(
        xyu, z16, W2, csr_sd, basea, cnt, out, n_nodes);
}

// Round 12
// 172.864 us; speedup vs baseline: 1.3645x; 1.1349x over previous
//
#include <hip/hip_runtime.h>

#define HIDDEN 128
#define NBUCKETS 20

typedef unsigned int uint32;
typedef unsigned short u16;
typedef unsigned long long u64;
typedef __attribute__((ext_vector_type(8))) short bf16x8;
typedef __attribute__((ext_vector_type(4))) float f32x4;

__device__ __forceinline__ u16 f32_to_bf16(float f) {
    uint32 u = __float_as_uint(f);
    return (u16)((u + 0x7fffu + ((u >> 16) & 1u)) >> 16);
}
__device__ __forceinline__ float bf_lo(uint32 u) { return __uint_as_float(u << 16); }
__device__ __forceinline__ float bf_hi(uint32 u) { return __uint_as_float(u & 0xffff0000u); }

// k1: W1T transpose+convert; zero cnt/cur/gcur; de_dot.
__global__ void prep_kernel(const float* __restrict__ W1, u16* __restrict__ W1T,
                            int* __restrict__ cnt, int* __restrict__ cur,
                            int* __restrict__ gcur, int n_nodes,
                            const float* __restrict__ table,
                            const float* __restrict__ W2,
                            float* __restrict__ de_dot) {
    int idx = blockIdx.x * 256 + threadIdx.x;
    int n = idx >> 7, k = idx & 127;
    int srow = (n < 128) ? k : (128 + k);
    W1T[idx] = f32_to_bf16(W1[srow * HIDDEN + (n & 127)]);
    for (int i = idx; i < n_nodes; i += 32768) { cnt[i] = 0; cur[i] = 0; }
    if (idx == 0) *gcur = 0;
    if (blockIdx.x == 0 && threadIdx.x < NBUCKETS) {
        float a = 0.f;
        for (int kk = 0; kk < HIDDEN; ++kk)
            a = fmaf(table[threadIdx.x * HIDDEN + kk], W2[HIDDEN + kk], a);
        de_dot[threadIdx.x] = a;
    }
}

// k2: fused degree-histogram + MFMA GEMM (one 16-row tile/block).
// Emits interleaved xy (per node, 64 uint2 {x_pair, y_pair}) with COALESCED
// 64B-per-lane stores (x re-read from lds_a during C readback), and z16.
__global__ __launch_bounds__(256)
void gemm_count_kernel(const float* __restrict__ x, const u16* __restrict__ W1T,
                       const int* __restrict__ tgt, int* __restrict__ cnt,
                       uint32* __restrict__ xyu, u16* __restrict__ z16,
                       int n_nodes, int n_edges) {
    __shared__ bf16x8 lds_a[16][16];
    __shared__ u16 lds_c[4][16][72];

    int tid = threadIdx.x;
    int e = blockIdx.x * 256 + tid;
    if (e < n_edges) atomicAdd(&cnt[tgt[e]], 1);

    int row_base = blockIdx.x * 16;
    if (row_base >= n_nodes) return;

    // A staging: thread -> (row = tid>>4, k-chunk c = tid&15).
    {
        int row = tid >> 4, c = tid & 15;
        int node = row_base + row;
        bf16x8 a = {};
        if (node < n_nodes) {
            const float4* xp = (const float4*)(x + (size_t)node * HIDDEN + c * 8);
            float4 v0 = xp[0], v1 = xp[1];
            a[0] = (short)f32_to_bf16(v0.x); a[1] = (short)f32_to_bf16(v0.y);
            a[2] = (short)f32_to_bf16(v0.z); a[3] = (short)f32_to_bf16(v0.w);
            a[4] = (short)f32_to_bf16(v1.x); a[5] = (short)f32_to_bf16(v1.y);
            a[6] = (short)f32_to_bf16(v1.z); a[7] = (short)f32_to_bf16(v1.w);
        }
        lds_a[c][row] = a;
    }
    __syncthreads();

    int wave = tid >> 6, lane = tid & 63;
    int m = lane & 15, kb = lane >> 4;

    bf16x8 afrag[4];
#pragma unroll
    for (int ks = 0; ks < 4; ++ks) afrag[ks] = lds_a[ks * 4 + kb][m];

#pragma unroll
    for (int ci = 0; ci < 4; ++ci) {
        int col = wave * 64 + ci * 16 + m;
        const u16* bp = W1T + (size_t)col * HIDDEN + kb * 8;
        f32x4 acc = {0.f, 0.f, 0.f, 0.f};
#pragma unroll
        for (int ks = 0; ks < 4; ++ks) {
            bf16x8 b = *(const bf16x8*)(bp + ks * 32);
            acc = __builtin_amdgcn_mfma_f32_16x16x32_bf16(afrag[ks], b, acc, 0, 0, 0);
        }
#pragma unroll
        for (int e2 = 0; e2 < 4; ++e2)
            lds_c[wave][kb * 4 + e2][ci * 16 + m] = f32_to_bf16(acc[e2]);
    }
    __syncthreads();

    // C readback: lane -> (row r = lane>>2, 16-col seg q = lane&3).
    // Waves 0,1 (y cols): interleave with x from lds_a -> 16 contiguous dwords.
    // Waves 2,3 (z cols): plain bf16x8 stores.
    {
        int r = lane >> 2, q = lane & 3;
        const u16* src = &lds_c[wave][r][q * 16];
        bf16x8 c0 = *(const bf16x8*)(src);
        bf16x8 c1 = *(const bf16x8*)(src + 8);
        int node = row_base + r;
        int colg = wave * 64 + q * 16;
        if (node < n_nodes) {
            if (colg < HIDDEN) {
                int ch = colg >> 3;             // x chunks ch, ch+1 cover these cols
                bf16x8 xa = lds_a[ch][r];
                bf16x8 xb = lds_a[ch + 1][r];
                const uint32* xu0 = (const uint32*)&xa;
                const uint32* xu1 = (const uint32*)&xb;
                const uint32* yu0 = (const uint32*)&c0;
                const uint32* yu1 = (const uint32*)&c1;
                uint32 ow[16];
#pragma unroll
                for (int i = 0; i < 4; ++i) { ow[2*i]   = xu0[i]; ow[2*i+1]   = yu0[i]; }
#pragma unroll
                for (int i = 0; i < 4; ++i) { ow[8+2*i] = xu1[i]; ow[8+2*i+1] = yu1[i]; }
                uint32* dst = xyu + (size_t)node * 128 + colg;  // dword 2p = pair p
#pragma unroll
                for (int i = 0; i < 4; ++i)
                    *(f32x4*)(dst + i * 4) = *(const f32x4*)(ow + i * 4);
            } else {
                u16* dst = z16 + (size_t)node * HIDDEN + colg - HIDDEN;
                *(bf16x8*)dst = c0;
                *(bf16x8*)(dst + 8) = c1;
            }
        }
    }
}

// k3: segment-base allocation: wave prefix-sum + one global atomic per wave.
__global__ void alloc_kernel(const int* __restrict__ cnt, int* __restrict__ base,
                             int* __restrict__ gcur, int n_nodes) {
    int i = blockIdx.x * 256 + threadIdx.x;
    int lane = threadIdx.x & 63;
    int deg = (i < n_nodes) ? cnt[i] : 0;
    int pre = deg;
#pragma unroll
    for (int d = 1; d < 64; d <<= 1) {
        int v = __shfl_up(pre, d, 64);
        if (lane >= d) pre += v;
    }
    int total = __shfl(pre, 63, 64);
    int wbase = 0;
    if (lane == 63) wbase = atomicAdd(gcur, total);
    wbase = __shfl(wbase, 63, 64);
    if (i < n_nodes) base[i] = wbase + pre - deg;
}

// k4: scatter edges into CSR order; record packs {ded_f32:32, s:32}.
__global__ void scatter_kernel(const int* __restrict__ edge_index,
                               const int* __restrict__ distances,
                               const int* __restrict__ base,
                               const float* __restrict__ de_dot,
                               int* __restrict__ cur,
                               u64* __restrict__ csr_sd,
                               int n_edges) {
    int e = blockIdx.x * blockDim.x + threadIdx.x;
    if (e >= n_edges) return;
    int s = edge_index[e];
    int t = edge_index[n_edges + e];
    float ded = de_dot[distances[e] / 50];
    int pos = atomicAdd(&cur[t], 1);
    csr_sd[base[t] + pos] = ((u64)__float_as_uint(ded) << 32) | (uint32)s;
}

// k5: one wave per node. 4-edge quarter-wave reduction: fold xor32 -> pair
// select -> fold xor16 -> quarter select -> 4-step butterfly. Sigmoid/exp
// issued once per 4 edges; single 8B xy gather per edge per lane.
__global__ void aggregate_kernel(const uint32* __restrict__ xyu,
                                 const u16* __restrict__ z16,
                                 const float* __restrict__ W2,
                                 const u64* __restrict__ csr_sd,
                                 const int* __restrict__ base_a,
                                 const int* __restrict__ cnt,
                                 float* __restrict__ out,
                                 int n_nodes) {
    int lane = threadIdx.x & 63;
    int t = blockIdx.x * (blockDim.x >> 6) + (threadIdx.x >> 6);
    if (t >= n_nodes) return;

    int base = base_a[t];
    int deg = cnt[t];
    const uint2* __restrict__ xyp = (const uint2*)xyu;

    uint32 zv = ((const uint32*)z16)[(size_t)t * 64 + lane];
    float z0 = bf_lo(zv), z1 = bf_hi(zv);
    float2 wv = *(const float2*)(W2 + lane * 2);

    float acc0 = 0.f, acc1 = 0.f, attsum = 0.f;
    bool hiHalf = lane >= 32;
    bool hiQuarter = (lane & 16) != 0;

    for (int b = 0; b < deg; b += 64) {
        int nb = min(64, deg - b);
        int s_l = 0;
        float ded_l = 0.f;
        if (lane < nb) {
            uint2 rec = *(const uint2*)(csr_sd + base + b + lane);
            s_l = (int)rec.x;
            ded_l = __uint_as_float(rec.y);
        }
        int j = 0;
        for (; j + 4 <= nb; j += 4) {
            int sA = __shfl(s_l, j, 64);
            int sB = __shfl(s_l, j + 1, 64);
            int sC = __shfl(s_l, j + 2, 64);
            int sD = __shfl(s_l, j + 3, 64);
            float dA = __shfl(ded_l, j, 64);
            float dB = __shfl(ded_l, j + 1, 64);
            float dC = __shfl(ded_l, j + 2, 64);
            float dD = __shfl(ded_l, j + 3, 64);
            uint2 va = xyp[(size_t)sA * 64 + lane];
            uint2 vb = xyp[(size_t)sB * 64 + lane];
            uint2 vc = xyp[(size_t)sC * 64 + lane];
            uint2 vd = xyp[(size_t)sD * 64 + lane];
            float h;
            h = bf_lo(va.y) + z0; h = fmaxf(h, 0.2f * h); float pA = h * wv.x;
            h = bf_hi(va.y) + z1; h = fmaxf(h, 0.2f * h); pA = fmaf(h, wv.y, pA);
            h = bf_lo(vb.y) + z0; h = fmaxf(h, 0.2f * h); float pB = h * wv.x;
            h = bf_hi(vb.y) + z1; h = fmaxf(h, 0.2f * h); pB = fmaf(h, wv.y, pB);
            h = bf_lo(vc.y) + z0; h = fmaxf(h, 0.2f * h); float pC = h * wv.x;
            h = bf_hi(vc.y) + z1; h = fmaxf(h, 0.2f * h); pC = fmaf(h, wv.y, pC);
            h = bf_lo(vd.y) + z0; h = fmaxf(h, 0.2f * h); float pD = h * wv.x;
            h = bf_hi(vd.y) + z1; h = fmaxf(h, 0.2f * h); pD = fmaf(h, wv.y, pD);
            // fold 64->32
            pA += __shfl_xor(pA, 32, 64);
            pB += __shfl_xor(pB, 32, 64);
            pC += __shfl_xor(pC, 32, 64);
            pD += __shfl_xor(pD, 32, 64);
            // halves: lo=A/ C, hi=B / D
            float rAB = hiHalf ? pB : pA;
            float rCD = hiHalf ? pD : pC;
            // fold 32->16
            rAB += __shfl_xor(rAB, 16, 64);
            rCD += __shfl_xor(rCD, 16, 64);
            // quarters: q0=A, q1=C, q2=B, q3=D
            float rr = hiQuarter ? rCD : rAB;
#pragma unroll
            for (int off = 8; off > 0; off >>= 1) rr += __shfl_xor(rr, off, 64);
            float ded_e = hiQuarter ? (hiHalf ? dD : dC) : (hiHalf ? dB : dA);
            float att = __expf(1.f / (1.f + __expf(-(rr + ded_e))));
            float attA = __shfl(att, 0, 64);
            float attC = __shfl(att, 16, 64);
            float attB = __shfl(att, 32, 64);
            float attD = __shfl(att, 48, 64);
            acc0 = fmaf(attA, bf_lo(va.x), acc0);
            acc1 = fmaf(attA, bf_hi(va.x), acc1);
            acc0 = fmaf(attB, bf_lo(vb.x), acc0);
            acc1 = fmaf(attB, bf_hi(vb.x), acc1);
            acc0 = fmaf(attC, bf_lo(vc.x), acc0);
            acc1 = fmaf(attC, bf_hi(vc.x), acc1);
            acc0 = fmaf(attD, bf_lo(vd.x), acc0);
            acc1 = fmaf(attD, bf_hi(vd.x), acc1);
            attsum += (attA + attB) + (attC + attD);
        }
        for (; j < nb; ++j) {
            int sA = __shfl(s_l, j, 64);
            float dA = __shfl(ded_l, j, 64);
            uint2 va = xyp[(size_t)sA * 64 + lane];
            float hA0 = bf_lo(va.y) + z0, hA1 = bf_hi(va.y) + z1;
            hA0 = fmaxf(hA0, 0.2f * hA0); hA1 = fmaxf(hA1, 0.2f * hA1);
            float pA = fmaf(hA0, wv.x, hA1 * wv.y);
#pragma unroll
            for (int off = 32; off > 0; off >>= 1) pA += __shfl_xor(pA, off, 64);
            float attA = __expf(1.f / (1.f + __expf(-(pA + dA))));
            acc0 = fmaf(attA, bf_lo(va.x), acc0);
            acc1 = fmaf(attA, bf_hi(va.x), acc1);
            attsum += attA;
        }
    }
    float inv = 1.f / (attsum + 1e-6f);
    float2 o;
    o.x = fmaxf(acc0 * inv, 0.f);
    o.y = fmaxf(acc1 * inv, 0.f);
    *(float2*)(out + (size_t)t * HIDDEN + lane * 2) = o;
}

static inline size_t align16(size_t v) { return (v + 15) & ~(size_t)15; }

extern "C" void kernel_launch(void* const* d_in, const int* in_sizes, int n_in,
                              void* d_out, int out_size, void* d_ws, size_t ws_size,
                              hipStream_t stream) {
    const float* x          = (const float*)d_in[0];
    const int*   edge_index = (const int*)d_in[1];
    const int*   distances  = (const int*)d_in[2];
    const float* W1         = (const float*)d_in[3];
    const float* W2         = (const float*)d_in[4];
    const float* table      = (const float*)d_in[5];

    int n_nodes = in_sizes[0] / HIDDEN;
    int n_edges = in_sizes[1] / 2;
    float* out = (float*)d_out;

    // Workspace layout (16B-aligned sections)
    char* p = (char*)d_ws;
    int* cnt      = (int*)p;                 p += align16((size_t)n_nodes * 4);
    int* cur      = (int*)p;                 p += align16((size_t)n_nodes * 4);
    int* basea    = (int*)p;                 p += align16((size_t)n_nodes * 4);
    int* gcur     = (int*)p;                 p += align16(16 * 4);
    u64* csr_sd   = (u64*)p;                 p += align16((size_t)n_edges * 8);
    float* de_dot = (float*)p;               p += align16(32 * 4);
    u16* W1T      = (u16*)p;                 p += align16(256 * HIDDEN * 2);
    u16* z16      = (u16*)p;                 p += align16((size_t)n_nodes * HIDDEN * 2);
    uint32* xyu   = (uint32*)p;              // n_nodes * 128 dwords (x/y interleaved)

    const int* tgt = edge_index + n_edges;

    prep_kernel<<<128, 256, 0, stream>>>(W1, W1T, cnt, cur, gcur, n_nodes,
                                         table, W2, de_dot);

    int ntiles = (n_nodes + 15) / 16;
    int eblocks = (n_edges + 255) / 256;
    int gblocks = (ntiles > eblocks) ? ntiles : eblocks;
    gemm_count_kernel<<<gblocks, 256, 0, stream>>>(x, W1T, tgt, cnt,
                                                   xyu, z16, n_nodes, n_edges);

    alloc_kernel<<<(n_nodes + 255) / 256, 256, 0, stream>>>(cnt, basea, gcur, n_nodes);

    scatter_kernel<<<eblocks, 256, 0, stream>>>(
        edge_index, distances, basea, de_dot, cur, csr_sd, n_edges);

    const int waves_per_block = 4;
    int ablocks = (n_nodes + waves_per_block - 1) / waves_per_block;
    aggregate_kernel<<<ablocks, 64 * waves_per_block, 0, stream>>>(
        xyu, z16, W2, csr_sd, basea, cnt, out, n_nodes);
}